// Round 8
// baseline (994.469 us; speedup 1.0000x reference)
//
#include <hip/hip_runtime.h>
#include <stdint.h>

// ---------------- bf16 helpers -------------------------------------------
__device__ __forceinline__ float bf2f(uint16_t u) {
    uint32_t x = ((uint32_t)u) << 16;
    float f;
    __builtin_memcpy(&f, &x, 4);
    return f;
}
__device__ __forceinline__ uint16_t f2bf(float f) {
    uint32_t u;
    __builtin_memcpy(&u, &f, 4);
    uint32_t r = (u + 0x7fffu + ((u >> 16) & 1u)) >> 16;  // RNE
    return (uint16_t)r;
}

typedef __attribute__((ext_vector_type(8))) short short8;   // 8 bf16 (MFMA A/B)
typedef __attribute__((ext_vector_type(4))) float floatx4;  // MFMA C/D

// async global->LDS, 16B per lane; LDS dest = wave-uniform base + lane*16
__device__ __forceinline__ void gload_lds16(const void* g, void* l) {
    __builtin_amdgcn_global_load_lds(
        (const __attribute__((address_space(1))) uint32_t*)g,
        (__attribute__((address_space(3))) uint32_t*)l, 16, 0, 0);
}

// ---------------- dtype detector ------------------------------------------
__global__ void detect_dtype(const uint16_t* __restrict__ x, int* __restrict__ flag) {
    int lane = threadIdx.x;  // 64 threads
    int cnt = 0;
    for (int i = 0; i < 8; ++i) {
        uint16_t u = x[lane * 8 + i];
        int e = (u >> 7) & 0xff;
        if (u == 0 || (e >= 96 && e <= 159)) ++cnt;
    }
    for (int off = 32; off; off >>= 1) cnt += __shfl_down(cnt, off);
    if (lane == 0) *flag = (cnt >= 448) ? 1 : 0;  // 1 = bf16 inputs, 0 = f32
}

// ---------------- f32 -> bf16 pre-convert (only when flag==0) --------------
// n divisible by 8. Same RNE rounding the GEMM staging used before.
__global__ __launch_bounds__(256) void cvt_to_bf16(const float* __restrict__ src,
                                                   uint16_t* __restrict__ dst,
                                                   long n, const int* __restrict__ flag) {
    if (*flag != 0) return;
    long stride = (long)gridDim.x * 256 * 8;
    for (long e = ((long)blockIdx.x * 256 + threadIdx.x) * 8; e < n; e += stride) {
        float4 a = *(const float4*)(src + e);
        float4 b = *(const float4*)(src + e + 4);
        uint4 o;
        o.x = (uint32_t)f2bf(a.x) | ((uint32_t)f2bf(a.y) << 16);
        o.y = (uint32_t)f2bf(a.z) | ((uint32_t)f2bf(a.w) << 16);
        o.z = (uint32_t)f2bf(b.x) | ((uint32_t)f2bf(b.y) << 16);
        o.w = (uint32_t)f2bf(b.z) | ((uint32_t)f2bf(b.w) << 16);
        *(uint4*)(dst + e) = o;
    }
}

// ---------------- Cayley via Newton-Schulz, all 8 matrices in ONE launch ---
// 4 NS iterations: residual ||S^2||^(2^4) ~ 4e-10, converged for f32.
struct CayleyJobs {
    const void* W[8];
    float* out[8];
};

template <int N>
__device__ __forceinline__ void cayley_block(const char* __restrict__ Wb, int isb,
                                             float* __restrict__ O,
                                             float* __restrict__ Ms,
                                             float* __restrict__ Ys,
                                             float* __restrict__ Ts) {
    constexpr int ST = (N == 80) ? 84 : (N == 48) ? 52 : 20;  // pad, mult of 4
    constexpr int RB = N / 16;  // 80->5, 48->3, 16->1
    const int tid = threadIdx.x;
    // stage: Ms = I+S, Ys = I-S  (S = W - W^T)
    for (int e = tid; e < N * N; e += 256) {
        int i = e / N, j = e - i * N;
        float wij, wji;
        if (isb) {
            wij = bf2f(((const uint16_t*)Wb)[i * N + j]);
            wji = bf2f(((const uint16_t*)Wb)[j * N + i]);
        } else {
            wij = ((const float*)Wb)[i * N + j];
            wji = ((const float*)Wb)[j * N + i];
        }
        float s = wij - wji;
        float idt = (i == j) ? 1.f : 0.f;
        Ms[i * ST + j] = idt + s;
        Ys[i * ST + j] = idt - s;
    }
    __syncthreads();
    const int i0 = (tid >> 4) * RB, j0 = (tid & 15) * RB;
    float acc[RB][RB];

#define MMUL(Amat, Bmat)                                                          \
    _Pragma("unroll") for (int r = 0; r < RB; ++r)                                \
        _Pragma("unroll") for (int c = 0; c < RB; ++c) acc[r][c] = 0.f;           \
    for (int k4 = 0; k4 < N / 4; ++k4) {                                          \
        float aa[RB][4];                                                          \
        _Pragma("unroll") for (int r = 0; r < RB; ++r) {                          \
            float4 a4 = *(const float4*)&Amat[(i0 + r) * ST + 4 * k4];            \
            aa[r][0] = a4.x; aa[r][1] = a4.y; aa[r][2] = a4.z; aa[r][3] = a4.w;   \
        }                                                                         \
        _Pragma("unroll") for (int kk = 0; kk < 4; ++kk) {                        \
            float b_[RB];                                                         \
            _Pragma("unroll") for (int c = 0; c < RB; ++c)                        \
                b_[c] = Bmat[(4 * k4 + kk) * ST + j0 + c];                        \
            _Pragma("unroll") for (int r = 0; r < RB; ++r)                        \
                _Pragma("unroll") for (int c = 0; c < RB; ++c)                    \
                    acc[r][c] = fmaf(aa[r][kk], b_[c], acc[r][c]);                \
        }                                                                         \
    }

    for (int it = 0; it < 4; ++it) {
        // Ts = 2I - Ms*Ys
        MMUL(Ms, Ys);
#pragma unroll
        for (int r = 0; r < RB; ++r)
#pragma unroll
            for (int c = 0; c < RB; ++c)
                Ts[(i0 + r) * ST + j0 + c] =
                    ((i0 + r) == (j0 + c) ? 2.f : 0.f) - acc[r][c];
        __syncthreads();
        // Ynew = Ys*Ts (in regs), write back after all reads complete
        MMUL(Ys, Ts);
        __syncthreads();
#pragma unroll
        for (int r = 0; r < RB; ++r)
#pragma unroll
            for (int c = 0; c < RB; ++c) Ys[(i0 + r) * ST + j0 + c] = acc[r][c];
        __syncthreads();
    }
    // Q = 2Y - Y*M
    MMUL(Ys, Ms);
#pragma unroll
    for (int r = 0; r < RB; ++r)
#pragma unroll
        for (int c = 0; c < RB; ++c)
            O[(i0 + r) * N + j0 + c] =
                2.f * Ys[(i0 + r) * ST + j0 + c] - acc[r][c];
#undef MMUL
}

__global__ __launch_bounds__(256) void cayley_all(CayleyJobs jobs,
                                                  const int* __restrict__ flag) {
    __shared__ float lds[3 * 80 * 84];  // 80,640 B: Ms | Ys | Ts
    const int isb = *flag;
    const int bid = blockIdx.x;
    int j, start, n;
    if (bid < 16)       { j = 0; start = 0;   n = 80; }
    else if (bid < 96)  { j = 1; start = 16;  n = 16; }
    else if (bid < 112) { j = 2; start = 96;  n = 48; }
    else if (bid < 160) { j = 3; start = 112; n = 16; }
    else if (bid < 176) { j = 4; start = 160; n = 48; }
    else if (bid < 224) { j = 5; start = 176; n = 16; }
    else if (bid < 240) { j = 6; start = 224; n = 80; }
    else                { j = 7; start = 240; n = 16; }
    const int sub = bid - start;
    const size_t esz = isb ? 2 : 4;
    const char* Wb = (const char*)jobs.W[j] + (size_t)sub * n * n * esz;
    float* O = jobs.out[j] + (size_t)sub * n * n;
    float* Ms = lds;
    float* Ys = lds + 80 * 84;
    float* Ts = lds + 2 * 80 * 84;
    if (n == 80)
        cayley_block<80>(Wb, isb, O, Ms, Ys, Ts);
    else if (n == 48)
        cayley_block<48>(Wb, isb, O, Ms, Ys, Ts);
    else
        cayley_block<16>(Wb, isb, O, Ms, Ys, Ts);
}

// ------- fused fold, ALL FOUR weights in one launch (grid.y = job) ---------
struct WeffJobs {
    const void* W[4];
    const float* Ac[4];
    const float* Bc[4];
    const void* scale[4];
    uint16_t* dst[4];
    int bdim[4];
    int Din[4];
    float esc[4];
};

template <int BD>
__device__ __forceinline__ void weff_body(const float* __restrict__ Ac,
                                          const float* __restrict__ Bc,
                                          uint16_t* __restrict__ WeffT,
                                          const float* __restrict__ Wrow,
                                          float* __restrict__ Tm, int o, float sc) {
    const int tid = threadIdx.x;
    constexpr int Din = 16 * BD;
    for (int e = tid; e < Din; e += 256) {
        int k = e / BD, c = e - k * BD;
        const float* Bm = Bc + c * 256 + k * 16;  // B[c][k][j]
        float s = 0.f;
#pragma unroll
        for (int j = 0; j < 16; ++j) s += Bm[j] * Wrow[j * BD + c];
        Tm[k * 80 + c] = s;
    }
    __syncthreads();
    for (int e = tid; e < Din; e += 256) {
        int k = e / BD, b = e - k * BD;
        const float4* Am = (const float4*)(Ac + ((size_t)k * BD + b) * BD);
        const float4* Tk = (const float4*)&Tm[k * 80];
        float s = 0.f;
#pragma unroll
        for (int c4 = 0; c4 < BD / 4; ++c4) {
            float4 a = Am[c4], t = Tk[c4];
            s += a.x * t.x + a.y * t.y + a.z * t.z + a.w * t.w;
        }
        WeffT[(size_t)o * Din + k * BD + b] = f2bf(s * sc);
    }
}

__global__ __launch_bounds__(256) void build_weff_all(WeffJobs jobs,
                                                      const int* __restrict__ flag) {
    const int isb = *flag;
    const int jb = blockIdx.y;
    const int bdim = jobs.bdim[jb], Din = jobs.Din[jb];
    const void* Wv = jobs.W[jb];
    __shared__ float Wrow[1280];
    __shared__ float Tm[16 * 80];
    const int o = blockIdx.x, tid = threadIdx.x;
    if (isb) {
        const uint16_t* W = (const uint16_t*)Wv;
        for (int i = tid; i < Din; i += 256) Wrow[i] = bf2f(W[(size_t)o * Din + i]);
    } else {
        const float* W = (const float*)Wv;
        for (int i = tid; i < Din; i += 256) Wrow[i] = W[(size_t)o * Din + i];
    }
    __syncthreads();
    float sc = (isb ? bf2f(((const uint16_t*)jobs.scale[jb])[o])
                    : ((const float*)jobs.scale[jb])[o]) *
               jobs.esc[jb];
    if (bdim == 80)
        weff_body<80>(jobs.Ac[jb], jobs.Bc[jb], jobs.dst[jb], Wrow, Tm, o, sc);
    else
        weff_body<48>(jobs.Ac[jb], jobs.Bc[jb], jobs.dst[jb], Wrow, Tm, o, sc);
}

// ---------------- C[M][N] = A[M][K]*Bt[N][K]^T (+bias), bf16 MFMA ----------
// 256x256 tile, BK=64, 8 waves, A ALWAYS bf16 (f32 inputs pre-converted).
// T4 counted-vmcnt pipeline: per tile STAGE(nxt) -> s_waitcnt vmcnt(8) ->
// s_barrier -> COMPUTE(cur) -> s_barrier. Each wave issues exactly 8
// gload_lds per tile (4 A + 4 B), so vmcnt(8) == "tile-t loads complete"
// (vmcnt completes in issue order, m135). Prefetch stays in flight across
// the barrier -- no vmcnt(0) drain in the main loop (m218: +38-73%).
// sched_barrier(0) fences guard against MFMA/ds_read reordering (rule #18).
// T2 both-sides swizzle and T1 XCD swizzle carried from R5/R6 (verified).
#define BM 256
#define BN 256
#define BK 64
__global__ __launch_bounds__(512, 2) void gemm_bt(const void* __restrict__ Av,
                                                  const uint16_t* __restrict__ Aalt,
                                                  const uint16_t* __restrict__ Bt,
                                                  void* __restrict__ Cv,
                                                  const void* __restrict__ biasv,
                                                  int M, int N, int K,
                                                  const int* __restrict__ flag,
                                                  int aforce, int flagio) {
    const int isb = aforce ? 1 : *flag;
    const bool io32 = flagio && (*flag == 0);
    const uint16_t* A = isb ? (const uint16_t*)Av : Aalt;
    __shared__ uint16_t As[2][BM * BK];  // 2 x 32 KB
    __shared__ uint16_t Bs[2][BN * BK];  // 2 x 32 KB
    // T1: bijective XCD swizzle of the flat workgroup id
    const int nwg = gridDim.x * gridDim.y;
    const int orig = blockIdx.y * gridDim.x + blockIdx.x;
    const int qc = nwg >> 3, rc = nwg & 7;
    const int xcd = orig & 7, sub = orig >> 3;
    const int wg = (xcd < rc ? xcd * (qc + 1) : rc * (qc + 1) + (xcd - rc) * qc) + sub;
    const int n0 = (wg % gridDim.x) * BN, m0 = (wg / gridDim.x) * BM;
    const int tid = threadIdx.x;
    const int wave = tid >> 6, lane = tid & 63;
    const int wm = (wave >> 2) * 128, wn = (wave & 3) * 64;  // 2M x 4N
    const int l16 = lane & 15, quad = lane >> 4;
    const int sw = (l16 & 7) << 4;  // frag-read XOR (row&7 == l16&7)
    const int NT = K / BK;          // 20 or 12

    floatx4 acc[8][4];
#pragma unroll
    for (int i = 0; i < 8; ++i)
#pragma unroll
        for (int j = 0; j < 4; ++j) {
            floatx4 z = {0.f, 0.f, 0.f, 0.f};
            acc[i][j] = z;
        }

    // staging: 32 chunks each for A and B (chunk = 8 rows x 128 B), 4/wave.
    // dest linear (base + lane*16B); global source col inverse-swizzled.
    const int srow = lane >> 3;                // row within chunk (= row&7)
    const int scol = ((lane & 7) ^ srow) * 8;  // inverse-swizzled col (u16)
    const uint16_t* gA[4];
    const uint16_t* gB[4];
    int ldsoff[4];  // u16 units
#pragma unroll
    for (int i = 0; i < 4; ++i) {
        int c = wave * 4 + i;
        int ar = m0 + c * 8 + srow;
        ar = ar < M ? ar : M - 1;  // ragged M: clamp load, mask store
        gA[i] = A + (size_t)ar * K + scol;
        gB[i] = Bt + (size_t)(n0 + c * 8 + srow) * K + scol;
        ldsoff[i] = c * 512;  // c*1024 bytes
    }

#define STAGE(buf, kt)                                                      \
    {                                                                       \
        _Pragma("unroll") for (int i = 0; i < 4; ++i) {                     \
            gload_lds16(gA[i] + (kt) * BK, &As[buf][0] + ldsoff[i]);        \
            gload_lds16(gB[i] + (kt) * BK, &Bs[buf][0] + ldsoff[i]);        \
        }                                                                   \
    }
#define COMPUTE(buf)                                                               \
    {                                                                              \
        _Pragma("unroll") for (int kc = 0; kc < 2; ++kc) {                         \
            short8 af[8], bfr[4];                                                  \
            _Pragma("unroll") for (int i = 0; i < 8; ++i)                          \
                af[i] = *(const short8*)((const char*)&As[buf][0] +                \
                                         (wm + i * 16 + l16) * 128 +               \
                                         ((kc * 64 + quad * 16) ^ sw));            \
            _Pragma("unroll") for (int j = 0; j < 4; ++j)                          \
                bfr[j] = *(const short8*)((const char*)&Bs[buf][0] +               \
                                          (wn + j * 16 + l16) * 128 +              \
                                          ((kc * 64 + quad * 16) ^ sw));           \
            _Pragma("unroll") for (int i = 0; i < 8; ++i)                          \
                _Pragma("unroll") for (int j = 0; j < 4; ++j)                      \
                    acc[i][j] = __builtin_amdgcn_mfma_f32_16x16x32_bf16(           \
                        af[i], bfr[j], acc[i][j], 0, 0, 0);                        \
        }                                                                          \
    }

    STAGE(0, 0);  // 8 outstanding
    for (int t = 0; t < NT - 1; ++t) {
        int cur = t & 1;
        STAGE(cur ^ 1, t + 1);  // 16 outstanding
        asm volatile("s_waitcnt vmcnt(8)" ::: "memory");  // tile-t loads done
        __builtin_amdgcn_sched_barrier(0);
        __builtin_amdgcn_s_barrier();  // all waves' tile-t data in LDS
        COMPUTE(cur);
        __builtin_amdgcn_sched_barrier(0);
        __builtin_amdgcn_s_barrier();  // reads done before buf reuse
    }
    asm volatile("s_waitcnt vmcnt(0)" ::: "memory");
    __builtin_amdgcn_sched_barrier(0);
    __builtin_amdgcn_s_barrier();
    COMPUTE((NT - 1) & 1);
#undef STAGE
#undef COMPUTE

    // C/D layout: col = lane&15, row = quad*4 + reg  [m89/m91-verified]
#pragma unroll
    for (int i = 0; i < 8; ++i) {
#pragma unroll
        for (int r = 0; r < 4; ++r) {
            int row = m0 + wm + i * 16 + quad * 4 + r;
            if (row < M) {
#pragma unroll
                for (int j = 0; j < 4; ++j) {
                    int col = n0 + wn + j * 16 + l16;
                    float v = acc[i][j][r];
                    if (biasv)
                        v += io32 ? ((const float*)biasv)[col]
                                  : bf2f(((const uint16_t*)biasv)[col]);
                    size_t idx = (size_t)row * N + col;
                    if (io32)
                        ((float*)Cv)[idx] = v;
                    else
                        ((uint16_t*)Cv)[idx] = f2bf(v);
                }
            }
        }
    }
}

// ---------------- MFMA attention: T=77, dh=64 ------------------------------
// K/V come from the fused KV GEMM: one [616][2560] buffer, K at col 0,
// V at col 1280 (row stride 2560).
__global__ __launch_bounds__(256) void attn_mfma(const uint16_t* __restrict__ kvb,
                                                 uint16_t* __restrict__ qbuf) {
    __shared__ uint16_t Ks[80 * 64];      // [t][d], stride 128B, XOR-swz
    __shared__ uint16_t VT[64 * 128];     // [d][t], stride 256B, XOR-swz, t>=77 zero
    __shared__ uint16_t Ph[4][16 * 128];  // per-wave P hi, [s][t] swz
    __shared__ uint16_t Pl[4][16 * 128];  // per-wave P lo
    const int b = blockIdx.z, h = blockIdx.y;
    const int tid = threadIdx.x;
    const int wave = tid >> 6, lane = tid & 63;
    const int l16 = lane & 15, quad = lane >> 4;

    // stage K (rows t<77 from global, else 0), swizzled
    for (int chunk = tid; chunk < 640; chunk += 256) {
        int t = chunk >> 3, c8 = chunk & 7;
        uint4 v = make_uint4(0u, 0u, 0u, 0u);
        if (t < 77)
            v = *(const uint4*)(kvb + ((size_t)(b * 77 + t)) * 2560 + h * 64 + c8 * 8);
        int byte = (c8 * 16) ^ ((t & 7) << 4);
        *(uint4*)((char*)&Ks[t * 64] + byte) = v;
    }
    // stage V transposed [d][t], t in [0,96), swizzled
    for (int e = tid; e < 96 * 64; e += 256) {
        int t = e >> 6, d = e & 63;
        uint16_t v = 0;
        if (t < 77) v = kvb[((size_t)(b * 77 + t)) * 2560 + 1280 + h * 64 + d];
        int byte = (t * 2) ^ ((d & 7) << 4);
        *(uint16_t*)((char*)&VT[d * 128] + byte) = v;
    }
    // zero the P pad band t in [80,96) (never written by groups)
    {
        uint16_t* PhW = Ph[wave];
        uint16_t* PlW = Pl[wave];
#pragma unroll
        for (int r0 = 0; r0 < 4; r0 += 2) {
            int t0 = 80 + quad * 4 + r0;
            int byte = (t0 * 2) ^ ((l16 & 7) << 4);
            *(uint32_t*)((char*)&PhW[l16 * 128] + byte) = 0u;
            *(uint32_t*)((char*)&PlW[l16 * 128] + byte) = 0u;
        }
    }
    __syncthreads();

    const int s_base = blockIdx.x * 256 + wave * 64;
    uint16_t* PhW = Ph[wave];
    uint16_t* PlW = Pl[wave];

    for (int g = 0; g < 4; ++g) {
        const int s0 = s_base + g * 16;
        // Q fragments straight from global (wave-coalesced 64B segments)
        const uint16_t* qrow = qbuf + ((size_t)(b * 4096 + s0 + l16)) * 1280 + h * 64;
        short8 qf0 = *(const short8*)(qrow + quad * 8);
        short8 qf1 = *(const short8*)(qrow + 32 + quad * 8);

        // scores^T[t][s]: acc over 5 t-tiles, k-dim = dh (2 chunks of 32)
        floatx4 sacc[5];
#pragma unroll
        for (int T = 0; T < 5; ++T) {
            floatx4 z = {0.f, 0.f, 0.f, 0.f};
            sacc[T] = z;
        }
#pragma unroll
        for (int T = 0; T < 5; ++T) {
            int trow = T * 16 + l16;
            const char* krow = (const char*)&Ks[trow * 64];
            int swz = (trow & 7) << 4;
            short8 ka0 = *(const short8*)(krow + ((quad * 16) ^ swz));
            short8 ka1 = *(const short8*)(krow + ((64 + quad * 16) ^ swz));
            sacc[T] = __builtin_amdgcn_mfma_f32_16x16x32_bf16(ka0, qf0, sacc[T], 0, 0, 0);
            sacc[T] = __builtin_amdgcn_mfma_f32_16x16x32_bf16(ka1, qf1, sacc[T], 0, 0, 0);
        }

        // softmax: lane holds 20 t-values for q-row s = s0+l16
        float sc[5][4];
        float m = -1e30f;
#pragma unroll
        for (int T = 0; T < 5; ++T)
#pragma unroll
            for (int r = 0; r < 4; ++r) {
                sc[T][r] = sacc[T][r];
                m = fmaxf(m, sc[T][r]);
            }
        m = fmaxf(m, __shfl_xor(m, 16));
        m = fmaxf(m, __shfl_xor(m, 32));
        float den = 0.f;
#pragma unroll
        for (int T = 0; T < 5; ++T)
#pragma unroll
            for (int r = 0; r < 4; ++r) {
                float p = __expf(sc[T][r] - m);
                if (T == 4 && r > 0) p = (quad == 3) ? 0.f : p;  // t>=77 mask
                sc[T][r] = p;
                den += p;
            }
        den += __shfl_xor(den, 16);
        den += __shfl_xor(den, 32);
        float rden = 1.f / den;

        // write normalized P as bf16 hi+lo into per-wave swizzled LDS
#pragma unroll
        for (int T = 0; T < 5; ++T) {
#pragma unroll
            for (int r0 = 0; r0 < 4; r0 += 2) {
                float p0 = sc[T][r0] * rden, p1 = sc[T][r0 + 1] * rden;
                uint16_t h0 = f2bf(p0), h1 = f2bf(p1);
                float l0f = p0 - bf2f(h0), l1f = p1 - bf2f(h1);
                uint16_t lo0 = f2bf(l0f), lo1 = f2bf(l1f);
                int t0 = T * 16 + quad * 4 + r0;
                int byte = (t0 * 2) ^ ((l16 & 7) << 4);
                *(uint32_t*)((char*)&PhW[l16 * 128] + byte) =
                    (uint32_t)h0 | ((uint32_t)h1 << 16);
                *(uint32_t*)((char*)&PlW[l16 * 128] + byte) =
                    (uint32_t)lo0 | ((uint32_t)lo1 << 16);
            }
        }
        // same-wave LDS write->read: in-order LDS pipe + drain
        asm volatile("s_waitcnt lgkmcnt(0)" ::: "memory");

        // PV: out[s][d] = P[s][t] * V[t][d], k-dim t = 96 (3 chunks)
        short8 pa_h[3], pa_l[3];
        {
            const char* prow_h = (const char*)&PhW[l16 * 128];
            const char* prow_l = (const char*)&PlW[l16 * 128];
            int swz = (l16 & 7) << 4;
#pragma unroll
            for (int c = 0; c < 3; ++c) {
                pa_h[c] = *(const short8*)(prow_h + ((c * 64 + quad * 16) ^ swz));
                pa_l[c] = *(const short8*)(prow_l + ((c * 64 + quad * 16) ^ swz));
            }
        }
        floatx4 oacc[4];
#pragma unroll
        for (int dt = 0; dt < 4; ++dt) {
            floatx4 z = {0.f, 0.f, 0.f, 0.f};
            oacc[dt] = z;
        }
#pragma unroll
        for (int dt = 0; dt < 4; ++dt) {
            int drow = dt * 16 + l16;
            const char* vrow = (const char*)&VT[drow * 128];
            int swz = (drow & 7) << 4;
#pragma unroll
            for (int c = 0; c < 3; ++c) {
                short8 vf = *(const short8*)(vrow + ((c * 64 + quad * 16) ^ swz));
                oacc[dt] = __builtin_amdgcn_mfma_f32_16x16x32_bf16(pa_h[c], vf, oacc[dt], 0, 0, 0);
                oacc[dt] = __builtin_amdgcn_mfma_f32_16x16x32_bf16(pa_l[c], vf, oacc[dt], 0, 0, 0);
            }
        }

        // store out in place over q rows: row = s0 + quad*4 + r, col = dt*16+l16
#pragma unroll
        for (int r = 0; r < 4; ++r) {
            int s = s0 + quad * 4 + r;
            uint16_t* orow = qbuf + ((size_t)(b * 4096 + s)) * 1280 + h * 64;
#pragma unroll
            for (int dt = 0; dt < 4; ++dt) orow[dt * 16 + l16] = f2bf(oacc[dt][r]);
        }
    }
}

// ---------------------------------------------------------------------------
extern "C" void kernel_launch(void* const* d_in, const int* in_sizes, int n_in,
                              void* d_out, int out_size, void* d_ws, size_t ws_size,
                              hipStream_t stream) {
    (void)in_sizes; (void)n_in; (void)out_size; (void)ws_size;

    // workspace layout (256B-aligned)
    char* ws = (char*)d_ws;
    int* flag      = (int*)(ws + 0);
    float* AcQ     = (float*)(ws + 409856);
    float* AcK     = (float*)(ws + 819456);
    float* AcV     = (float*)(ws + 966912);
    float* AcO     = (float*)(ws + 1114368);
    float* BcQ     = (float*)(ws + 1523968);
    float* BcK     = (float*)(ws + 1605888);
    float* BcV     = (float*)(ws + 1655040);
    float* BcO     = (float*)(ws + 1704192);
    uint16_t* WqT  = (uint16_t*)(ws + 1786112);   // [1280][1280]
    uint16_t* WkT  = (uint16_t*)(ws + 5062912);   // [1280][768], contiguous with
    uint16_t* WvT  = (uint16_t*)(ws + 7028992);   //   WvT -> acts as [2560][768]
    uint16_t* WoT  = (uint16_t*)(ws + 8995072);   // [1280][1280]
    uint16_t* kvb  = (uint16_t*)(ws + 12271872);  // [616][2560] (K|V fused)
    uint16_t* qb   = (uint16_t*)(ws + 15425792);  // [32768][1280]

    // bf16 scratch for f32 inputs lives in d_out (f32-out case: 168 MB >> 85 MB
    // needed; consumed by Q/KV projections BEFORE the O-proj writes d_out).
    uint16_t* hs16  = (uint16_t*)d_out;                       // [32768][1280] bf16
    uint16_t* enc16 = (uint16_t*)((char*)d_out + 83886080);   // [616][768] bf16

    detect_dtype<<<1, 64, 0, stream>>>((const uint16_t*)d_in[0], flag);

    // Pre-convert f32 inputs to bf16 (no-op when flag==1)
    cvt_to_bf16<<<2048, 256, 0, stream>>>((const float*)d_in[0], hs16,
                                          (long)32768 * 1280, flag);
    cvt_to_bf16<<<256, 256, 0, stream>>>((const float*)d_in[1], enc16,
                                         (long)616 * 768, flag);

    // Cayley (Newton-Schulz): all 8 matrices, both dtypes, ONE launch.
    CayleyJobs cj;
    cj.W[0] = d_in[2]; cj.out[0] = AcQ;
    cj.W[1] = d_in[3]; cj.out[1] = BcQ;
    cj.W[2] = d_in[4]; cj.out[2] = AcK;
    cj.W[3] = d_in[5]; cj.out[3] = BcK;
    cj.W[4] = d_in[6]; cj.out[4] = AcV;
    cj.W[5] = d_in[7]; cj.out[5] = BcV;
    cj.W[6] = d_in[8]; cj.out[6] = AcO;
    cj.W[7] = d_in[9]; cj.out[7] = BcO;
    cayley_all<<<320, 256, 0, stream>>>(cj, flag);

    // Fold Monarch + W^T + scale -> WeffT (bf16), ONE launch for all four.
    // Q gets an extra 0.125 = dh^-0.5 (exact pow2) so attention needs no scale.
    WeffJobs wj;
    wj.W[0] = d_in[10]; wj.Ac[0] = AcQ; wj.Bc[0] = BcQ; wj.scale[0] = d_in[15];
    wj.dst[0] = WqT; wj.bdim[0] = 80; wj.Din[0] = 1280; wj.esc[0] = 0.125f;
    wj.W[1] = d_in[11]; wj.Ac[1] = AcK; wj.Bc[1] = BcK; wj.scale[1] = d_in[16];
    wj.dst[1] = WkT; wj.bdim[1] = 48; wj.Din[1] = 768; wj.esc[1] = 1.0f;
    wj.W[2] = d_in[12]; wj.Ac[2] = AcV; wj.Bc[2] = BcV; wj.scale[2] = d_in[17];
    wj.dst[2] = WvT; wj.bdim[2] = 48; wj.Din[2] = 768; wj.esc[2] = 1.0f;
    wj.W[3] = d_in[13]; wj.Ac[3] = AcO; wj.Bc[3] = BcO; wj.scale[3] = d_in[18];
    wj.dst[3] = WoT; wj.bdim[3] = 80; wj.Din[3] = 1280; wj.esc[3] = 1.0f;
    build_weff_all<<<dim3(1280, 4), 256, 0, stream>>>(wj, flag);

    // Projections (A always bf16: input-or-scratch; C bf16 internal)
    gemm_bt<<<dim3(5, 128), 512, 0, stream>>>(d_in[0], hs16, WqT, qb, nullptr,
                                              32768, 1280, 1280, flag, 0, 0);
    // K and V in ONE GEMM: B = [WkT;WvT] (contiguous), C = kvb [616][2560]
    gemm_bt<<<dim3(10, 3), 512, 0, stream>>>(d_in[1], enc16, WkT, kvb, nullptr,
                                             616, 2560, 768, flag, 0, 0);

    // Attention (in-place on qb, always bf16), MFMA path
    attn_mfma<<<dim3(16, 20, 8), 256, 0, stream>>>(kvb, qb);

    // Output projection + bias -> d_out; A = qb (bf16), out dtype follows flag
    gemm_bt<<<dim3(5, 128), 512, 0, stream>>>(qb, nullptr, WoT, d_out, d_in[14],
                                              32768, 1280, 1280, flag, 1, 1);
}

// Round 9
// 932.890 us; speedup vs baseline: 1.0660x; 1.0660x over previous
//
#include <hip/hip_runtime.h>
#include <stdint.h>

// ---------------- bf16 helpers -------------------------------------------
__device__ __forceinline__ float bf2f(uint16_t u) {
    uint32_t x = ((uint32_t)u) << 16;
    float f;
    __builtin_memcpy(&f, &x, 4);
    return f;
}
__device__ __forceinline__ uint16_t f2bf(float f) {
    uint32_t u;
    __builtin_memcpy(&u, &f, 4);
    uint32_t r = (u + 0x7fffu + ((u >> 16) & 1u)) >> 16;  // RNE
    return (uint16_t)r;
}

typedef __attribute__((ext_vector_type(8))) short short8;   // 8 bf16 (MFMA A/B)
typedef __attribute__((ext_vector_type(4))) float floatx4;  // MFMA C/D

// async global->LDS, 16B per lane; LDS dest = wave-uniform base + lane*16
__device__ __forceinline__ void gload_lds16(const void* g, void* l) {
    __builtin_amdgcn_global_load_lds(
        (const __attribute__((address_space(1))) uint32_t*)g,
        (__attribute__((address_space(3))) uint32_t*)l, 16, 0, 0);
}

// ---------------- dtype detector ------------------------------------------
__global__ void detect_dtype(const uint16_t* __restrict__ x, int* __restrict__ flag) {
    int lane = threadIdx.x;  // 64 threads
    int cnt = 0;
    for (int i = 0; i < 8; ++i) {
        uint16_t u = x[lane * 8 + i];
        int e = (u >> 7) & 0xff;
        if (u == 0 || (e >= 96 && e <= 159)) ++cnt;
    }
    for (int off = 32; off; off >>= 1) cnt += __shfl_down(cnt, off);
    if (lane == 0) *flag = (cnt >= 448) ? 1 : 0;  // 1 = bf16 inputs, 0 = f32
}

// ---------------- f32 -> bf16 pre-convert (only when flag==0) --------------
__global__ __launch_bounds__(256) void cvt_to_bf16(const float* __restrict__ src,
                                                   uint16_t* __restrict__ dst,
                                                   long n, const int* __restrict__ flag) {
    if (*flag != 0) return;
    long stride = (long)gridDim.x * 256 * 8;
    for (long e = ((long)blockIdx.x * 256 + threadIdx.x) * 8; e < n; e += stride) {
        float4 a = *(const float4*)(src + e);
        float4 b = *(const float4*)(src + e + 4);
        uint4 o;
        o.x = (uint32_t)f2bf(a.x) | ((uint32_t)f2bf(a.y) << 16);
        o.y = (uint32_t)f2bf(a.z) | ((uint32_t)f2bf(a.w) << 16);
        o.z = (uint32_t)f2bf(b.x) | ((uint32_t)f2bf(b.y) << 16);
        o.w = (uint32_t)f2bf(b.z) | ((uint32_t)f2bf(b.w) << 16);
        *(uint4*)(dst + e) = o;
    }
}

// ---------------- Cayley via Newton-Schulz, all 8 matrices in ONE launch ---
struct CayleyJobs {
    const void* W[8];
    float* out[8];
};

template <int N>
__device__ __forceinline__ void cayley_block(const char* __restrict__ Wb, int isb,
                                             float* __restrict__ O,
                                             float* __restrict__ Ms,
                                             float* __restrict__ Ys,
                                             float* __restrict__ Ts) {
    constexpr int ST = (N == 80) ? 84 : (N == 48) ? 52 : 20;  // pad, mult of 4
    constexpr int RB = N / 16;  // 80->5, 48->3, 16->1
    const int tid = threadIdx.x;
    for (int e = tid; e < N * N; e += 256) {
        int i = e / N, j = e - i * N;
        float wij, wji;
        if (isb) {
            wij = bf2f(((const uint16_t*)Wb)[i * N + j]);
            wji = bf2f(((const uint16_t*)Wb)[j * N + i]);
        } else {
            wij = ((const float*)Wb)[i * N + j];
            wji = ((const float*)Wb)[j * N + i];
        }
        float s = wij - wji;
        float idt = (i == j) ? 1.f : 0.f;
        Ms[i * ST + j] = idt + s;
        Ys[i * ST + j] = idt - s;
    }
    __syncthreads();
    const int i0 = (tid >> 4) * RB, j0 = (tid & 15) * RB;
    float acc[RB][RB];

#define MMUL(Amat, Bmat)                                                          \
    _Pragma("unroll") for (int r = 0; r < RB; ++r)                                \
        _Pragma("unroll") for (int c = 0; c < RB; ++c) acc[r][c] = 0.f;           \
    for (int k4 = 0; k4 < N / 4; ++k4) {                                          \
        float aa[RB][4];                                                          \
        _Pragma("unroll") for (int r = 0; r < RB; ++r) {                          \
            float4 a4 = *(const float4*)&Amat[(i0 + r) * ST + 4 * k4];            \
            aa[r][0] = a4.x; aa[r][1] = a4.y; aa[r][2] = a4.z; aa[r][3] = a4.w;   \
        }                                                                         \
        _Pragma("unroll") for (int kk = 0; kk < 4; ++kk) {                        \
            float b_[RB];                                                         \
            _Pragma("unroll") for (int c = 0; c < RB; ++c)                        \
                b_[c] = Bmat[(4 * k4 + kk) * ST + j0 + c];                        \
            _Pragma("unroll") for (int r = 0; r < RB; ++r)                        \
                _Pragma("unroll") for (int c = 0; c < RB; ++c)                    \
                    acc[r][c] = fmaf(aa[r][kk], b_[c], acc[r][c]);                \
        }                                                                         \
    }

    for (int it = 0; it < 4; ++it) {
        MMUL(Ms, Ys);
#pragma unroll
        for (int r = 0; r < RB; ++r)
#pragma unroll
            for (int c = 0; c < RB; ++c)
                Ts[(i0 + r) * ST + j0 + c] =
                    ((i0 + r) == (j0 + c) ? 2.f : 0.f) - acc[r][c];
        __syncthreads();
        MMUL(Ys, Ts);
        __syncthreads();
#pragma unroll
        for (int r = 0; r < RB; ++r)
#pragma unroll
            for (int c = 0; c < RB; ++c) Ys[(i0 + r) * ST + j0 + c] = acc[r][c];
        __syncthreads();
    }
    MMUL(Ys, Ms);
#pragma unroll
    for (int r = 0; r < RB; ++r)
#pragma unroll
        for (int c = 0; c < RB; ++c)
            O[(i0 + r) * N + j0 + c] =
                2.f * Ys[(i0 + r) * ST + j0 + c] - acc[r][c];
#undef MMUL
}

__global__ __launch_bounds__(256) void cayley_all(CayleyJobs jobs,
                                                  const int* __restrict__ flag) {
    __shared__ float lds[3 * 80 * 84];  // 80,640 B: Ms | Ys | Ts
    const int isb = *flag;
    const int bid = blockIdx.x;
    int j, start, n;
    if (bid < 16)       { j = 0; start = 0;   n = 80; }
    else if (bid < 96)  { j = 1; start = 16;  n = 16; }
    else if (bid < 112) { j = 2; start = 96;  n = 48; }
    else if (bid < 160) { j = 3; start = 112; n = 16; }
    else if (bid < 176) { j = 4; start = 160; n = 48; }
    else if (bid < 224) { j = 5; start = 176; n = 16; }
    else if (bid < 240) { j = 6; start = 224; n = 80; }
    else                { j = 7; start = 240; n = 16; }
    const int sub = bid - start;
    const size_t esz = isb ? 2 : 4;
    const char* Wb = (const char*)jobs.W[j] + (size_t)sub * n * n * esz;
    float* O = jobs.out[j] + (size_t)sub * n * n;
    float* Ms = lds;
    float* Ys = lds + 80 * 84;
    float* Ts = lds + 2 * 80 * 84;
    if (n == 80)
        cayley_block<80>(Wb, isb, O, Ms, Ys, Ts);
    else if (n == 48)
        cayley_block<48>(Wb, isb, O, Ms, Ys, Ts);
    else
        cayley_block<16>(Wb, isb, O, Ms, Ys, Ts);
}

// ------- fused fold, ALL FOUR weights in one launch (grid.y = job) ---------
struct WeffJobs {
    const void* W[4];
    const float* Ac[4];
    const float* Bc[4];
    const void* scale[4];
    uint16_t* dst[4];
    int bdim[4];
    int Din[4];
    float esc[4];
};

template <int BD>
__device__ __forceinline__ void weff_body(const float* __restrict__ Ac,
                                          const float* __restrict__ Bc,
                                          uint16_t* __restrict__ WeffT,
                                          const float* __restrict__ Wrow,
                                          float* __restrict__ Tm, int o, float sc) {
    const int tid = threadIdx.x;
    constexpr int Din = 16 * BD;
    for (int e = tid; e < Din; e += 256) {
        int k = e / BD, c = e - k * BD;
        const float* Bm = Bc + c * 256 + k * 16;  // B[c][k][j]
        float s = 0.f;
#pragma unroll
        for (int j = 0; j < 16; ++j) s += Bm[j] * Wrow[j * BD + c];
        Tm[k * 80 + c] = s;
    }
    __syncthreads();
    for (int e = tid; e < Din; e += 256) {
        int k = e / BD, b = e - k * BD;
        const float4* Am = (const float4*)(Ac + ((size_t)k * BD + b) * BD);
        const float4* Tk = (const float4*)&Tm[k * 80];
        float s = 0.f;
#pragma unroll
        for (int c4 = 0; c4 < BD / 4; ++c4) {
            float4 a = Am[c4], t = Tk[c4];
            s += a.x * t.x + a.y * t.y + a.z * t.z + a.w * t.w;
        }
        WeffT[(size_t)o * Din + k * BD + b] = f2bf(s * sc);
    }
}

__global__ __launch_bounds__(256) void build_weff_all(WeffJobs jobs,
                                                      const int* __restrict__ flag) {
    const int isb = *flag;
    const int jb = blockIdx.y;
    const int bdim = jobs.bdim[jb], Din = jobs.Din[jb];
    const void* Wv = jobs.W[jb];
    __shared__ float Wrow[1280];
    __shared__ float Tm[16 * 80];
    const int o = blockIdx.x, tid = threadIdx.x;
    if (isb) {
        const uint16_t* W = (const uint16_t*)Wv;
        for (int i = tid; i < Din; i += 256) Wrow[i] = bf2f(W[(size_t)o * Din + i]);
    } else {
        const float* W = (const float*)Wv;
        for (int i = tid; i < Din; i += 256) Wrow[i] = W[(size_t)o * Din + i];
    }
    __syncthreads();
    float sc = (isb ? bf2f(((const uint16_t*)jobs.scale[jb])[o])
                    : ((const float*)jobs.scale[jb])[o]) *
               jobs.esc[jb];
    if (bdim == 80)
        weff_body<80>(jobs.Ac[jb], jobs.Bc[jb], jobs.dst[jb], Wrow, Tm, o, sc);
    else
        weff_body<48>(jobs.Ac[jb], jobs.Bc[jb], jobs.dst[jb], Wrow, Tm, o, sc);
}

// ---------------- C[M][N] = A[M][K]*Bt[N][K]^T (+bias), bf16 MFMA ----------
// 256x256 tile, BK=64, 8 waves, A ALWAYS bf16 (f32 inputs pre-converted).
// m201-style 8-phase rhythm: per K-tile, 4 phases of
//   { ds_read 8 frags ; (phases 0-1: issue 4 prefetch gloads into buf[nxt]) ;
//     lgkmcnt(0)+sched_barrier ; setprio(1) 16 MFMA setprio(0) ; s_barrier }
// vmcnt(0) only at tile boundary (only tile-t+1 loads outstanding, issued
// ~3 phases earlier -> latency hidden). bfr frags persist across the two
// mh-phases of a kc so ds_read count stays 24/tile. T5 setprio pays only in
// this phase-split regime (m218b). T2 both-sides swizzle + T1 XCD swizzle
// carried from R5-R7 (verified, conflicts == 0). Buffer hazards: tile-t
// ds_reads hit buf[cur] only; buf[nxt]'s last readers (tile t-1) finished
// before the end-of-(t-1) barrier, which precedes any tile-t gload issue.
#define BM 256
#define BN 256
#define BK 64
__global__ __launch_bounds__(512, 2) void gemm_bt(const void* __restrict__ Av,
                                                  const uint16_t* __restrict__ Aalt,
                                                  const uint16_t* __restrict__ Bt,
                                                  void* __restrict__ Cv,
                                                  const void* __restrict__ biasv,
                                                  int M, int N, int K,
                                                  const int* __restrict__ flag,
                                                  int aforce, int flagio) {
    const int isb = aforce ? 1 : *flag;
    const bool io32 = flagio && (*flag == 0);
    const uint16_t* A = isb ? (const uint16_t*)Av : Aalt;
    __shared__ uint16_t As[2][BM * BK];  // 2 x 32 KB
    __shared__ uint16_t Bs[2][BN * BK];  // 2 x 32 KB
    // T1: bijective XCD swizzle of the flat workgroup id
    const int nwg = gridDim.x * gridDim.y;
    const int orig = blockIdx.y * gridDim.x + blockIdx.x;
    const int qc = nwg >> 3, rc = nwg & 7;
    const int xcd = orig & 7, sub = orig >> 3;
    const int wg = (xcd < rc ? xcd * (qc + 1) : rc * (qc + 1) + (xcd - rc) * qc) + sub;
    const int n0 = (wg % gridDim.x) * BN, m0 = (wg / gridDim.x) * BM;
    const int tid = threadIdx.x;
    const int wave = tid >> 6, lane = tid & 63;
    const int wm = (wave >> 2) * 128, wn = (wave & 3) * 64;  // 2M x 4N
    const int l16 = lane & 15, quad = lane >> 4;
    const int sw = (l16 & 7) << 4;  // frag-read XOR (row&7 == l16&7)
    const int NT = K / BK;          // 20 or 12

    floatx4 acc[8][4];
#pragma unroll
    for (int i = 0; i < 8; ++i)
#pragma unroll
        for (int j = 0; j < 4; ++j) {
            floatx4 z = {0.f, 0.f, 0.f, 0.f};
            acc[i][j] = z;
        }

    // staging: 32 chunks each for A and B (chunk = 8 rows x 128 B), 4/wave.
    // dest linear (base + lane*16B); global source col inverse-swizzled.
    const int srow = lane >> 3;                // row within chunk (= row&7)
    const int scol = ((lane & 7) ^ srow) * 8;  // inverse-swizzled col (u16)
    const uint16_t* gA[4];
    const uint16_t* gB[4];
    int ldsoff[4];  // u16 units
#pragma unroll
    for (int i = 0; i < 4; ++i) {
        int c = wave * 4 + i;
        int ar = m0 + c * 8 + srow;
        ar = ar < M ? ar : M - 1;  // ragged M: clamp load, mask store
        gA[i] = A + (size_t)ar * K + scol;
        gB[i] = Bt + (size_t)(n0 + c * 8 + srow) * K + scol;
        ldsoff[i] = c * 512;  // c*1024 bytes
    }

    // prologue: tile 0 into buf 0 (8 outstanding)
#pragma unroll
    for (int i = 0; i < 4; ++i) {
        gload_lds16(gA[i], &As[0][0] + ldsoff[i]);
        gload_lds16(gB[i], &Bs[0][0] + ldsoff[i]);
    }

    for (int t = 0; t < NT; ++t) {
        const int cur = t & 1, nxt = cur ^ 1;
        const char* Ab = (const char*)&As[cur][0];
        const char* Bb = (const char*)&Bs[cur][0];
        // tile boundary: wait own loads, then all-waves barrier
        asm volatile("s_waitcnt vmcnt(0)" ::: "memory");
        __builtin_amdgcn_sched_barrier(0);
        __builtin_amdgcn_s_barrier();
        short8 bfr[4];
#pragma unroll
        for (int kc = 0; kc < 2; ++kc) {
            const int kb = (kc * 64 + quad * 16) ^ sw;
            {  // phase mh=0: read bfr(kc) + af rows 0..3; prefetch A(t+1)
                short8 afr[4];
#pragma unroll
                for (int j = 0; j < 4; ++j)
                    bfr[j] = *(const short8*)(Bb + (wn + j * 16 + l16) * 128 + kb);
#pragma unroll
                for (int r = 0; r < 4; ++r)
                    afr[r] = *(const short8*)(Ab + (wm + r * 16 + l16) * 128 + kb);
                if (kc == 0 && t + 1 < NT) {
#pragma unroll
                    for (int i = 0; i < 4; ++i)
                        gload_lds16(gA[i] + (t + 1) * BK, &As[nxt][0] + ldsoff[i]);
                }
                asm volatile("s_waitcnt lgkmcnt(0)" ::: "memory");
                __builtin_amdgcn_sched_barrier(0);
                __builtin_amdgcn_s_setprio(1);
#pragma unroll
                for (int r = 0; r < 4; ++r)
#pragma unroll
                    for (int j = 0; j < 4; ++j)
                        acc[r][j] = __builtin_amdgcn_mfma_f32_16x16x32_bf16(
                            afr[r], bfr[j], acc[r][j], 0, 0, 0);
                __builtin_amdgcn_s_setprio(0);
                __builtin_amdgcn_sched_barrier(0);
                __builtin_amdgcn_s_barrier();
            }
            {  // phase mh=1: read af rows 4..7 (bfr kept); prefetch B(t+1)
                short8 afr[4];
#pragma unroll
                for (int r = 0; r < 4; ++r)
                    afr[r] = *(const short8*)(Ab + (wm + (r + 4) * 16 + l16) * 128 + kb);
                if (kc == 0 && t + 1 < NT) {
#pragma unroll
                    for (int i = 0; i < 4; ++i)
                        gload_lds16(gB[i] + (t + 1) * BK, &Bs[nxt][0] + ldsoff[i]);
                }
                asm volatile("s_waitcnt lgkmcnt(0)" ::: "memory");
                __builtin_amdgcn_sched_barrier(0);
                __builtin_amdgcn_s_setprio(1);
#pragma unroll
                for (int r = 0; r < 4; ++r)
#pragma unroll
                    for (int j = 0; j < 4; ++j)
                        acc[r + 4][j] = __builtin_amdgcn_mfma_f32_16x16x32_bf16(
                            afr[r], bfr[j], acc[r + 4][j], 0, 0, 0);
                __builtin_amdgcn_s_setprio(0);
                __builtin_amdgcn_sched_barrier(0);
                __builtin_amdgcn_s_barrier();
            }
        }
    }

    // C/D layout: col = lane&15, row = quad*4 + reg  [m89/m91-verified]
#pragma unroll
    for (int i = 0; i < 8; ++i) {
#pragma unroll
        for (int r = 0; r < 4; ++r) {
            int row = m0 + wm + i * 16 + quad * 4 + r;
            if (row < M) {
#pragma unroll
                for (int j = 0; j < 4; ++j) {
                    int col = n0 + wn + j * 16 + l16;
                    float v = acc[i][j][r];
                    if (biasv)
                        v += io32 ? ((const float*)biasv)[col]
                                  : bf2f(((const uint16_t*)biasv)[col]);
                    size_t idx = (size_t)row * N + col;
                    if (io32)
                        ((float*)Cv)[idx] = v;
                    else
                        ((uint16_t*)Cv)[idx] = f2bf(v);
                }
            }
        }
    }
}

// ---------------- MFMA attention: T=77, dh=64 ------------------------------
// K/V come from the fused KV GEMM: one [616][2560] buffer, K at col 0,
// V at col 1280 (row stride 2560).
__global__ __launch_bounds__(256) void attn_mfma(const uint16_t* __restrict__ kvb,
                                                 uint16_t* __restrict__ qbuf) {
    __shared__ uint16_t Ks[80 * 64];      // [t][d], stride 128B, XOR-swz
    __shared__ uint16_t VT[64 * 128];     // [d][t], stride 256B, XOR-swz, t>=77 zero
    __shared__ uint16_t Ph[4][16 * 128];  // per-wave P hi, [s][t] swz
    __shared__ uint16_t Pl[4][16 * 128];  // per-wave P lo
    const int b = blockIdx.z, h = blockIdx.y;
    const int tid = threadIdx.x;
    const int wave = tid >> 6, lane = tid & 63;
    const int l16 = lane & 15, quad = lane >> 4;

    // stage K (rows t<77 from global, else 0), swizzled
    for (int chunk = tid; chunk < 640; chunk += 256) {
        int t = chunk >> 3, c8 = chunk & 7;
        uint4 v = make_uint4(0u, 0u, 0u, 0u);
        if (t < 77)
            v = *(const uint4*)(kvb + ((size_t)(b * 77 + t)) * 2560 + h * 64 + c8 * 8);
        int byte = (c8 * 16) ^ ((t & 7) << 4);
        *(uint4*)((char*)&Ks[t * 64] + byte) = v;
    }
    // stage V transposed [d][t], vectorized uint4 global reads (d%8==0 per
    // chunk so (d+i)&7 == i), scalar swizzled LDS scatter
    for (int e = tid * 8; e < 96 * 64; e += 256 * 8) {
        int t = e >> 6, d = e & 63;
        uint4 v = make_uint4(0u, 0u, 0u, 0u);
        if (t < 77)
            v = *(const uint4*)(kvb + ((size_t)(b * 77 + t)) * 2560 + 1280 + h * 64 + d);
        const uint16_t* pv = (const uint16_t*)&v;
#pragma unroll
        for (int i = 0; i < 8; ++i) {
            int byte = (t * 2) ^ (i << 4);
            *(uint16_t*)((char*)&VT[(d + i) * 128] + byte) = pv[i];
        }
    }
    // zero the P pad band t in [80,96) (never written by groups)
    {
        uint16_t* PhW = Ph[wave];
        uint16_t* PlW = Pl[wave];
#pragma unroll
        for (int r0 = 0; r0 < 4; r0 += 2) {
            int t0 = 80 + quad * 4 + r0;
            int byte = (t0 * 2) ^ ((l16 & 7) << 4);
            *(uint32_t*)((char*)&PhW[l16 * 128] + byte) = 0u;
            *(uint32_t*)((char*)&PlW[l16 * 128] + byte) = 0u;
        }
    }
    __syncthreads();

    const int s_base = blockIdx.x * 256 + wave * 64;
    uint16_t* PhW = Ph[wave];
    uint16_t* PlW = Pl[wave];

    for (int g = 0; g < 4; ++g) {
        const int s0 = s_base + g * 16;
        // Q fragments straight from global (wave-coalesced 64B segments)
        const uint16_t* qrow = qbuf + ((size_t)(b * 4096 + s0 + l16)) * 1280 + h * 64;
        short8 qf0 = *(const short8*)(qrow + quad * 8);
        short8 qf1 = *(const short8*)(qrow + 32 + quad * 8);

        // scores^T[t][s]: acc over 5 t-tiles, k-dim = dh (2 chunks of 32)
        floatx4 sacc[5];
#pragma unroll
        for (int T = 0; T < 5; ++T) {
            floatx4 z = {0.f, 0.f, 0.f, 0.f};
            sacc[T] = z;
        }
#pragma unroll
        for (int T = 0; T < 5; ++T) {
            int trow = T * 16 + l16;
            const char* krow = (const char*)&Ks[trow * 64];
            int swz = (trow & 7) << 4;
            short8 ka0 = *(const short8*)(krow + ((quad * 16) ^ swz));
            short8 ka1 = *(const short8*)(krow + ((64 + quad * 16) ^ swz));
            sacc[T] = __builtin_amdgcn_mfma_f32_16x16x32_bf16(ka0, qf0, sacc[T], 0, 0, 0);
            sacc[T] = __builtin_amdgcn_mfma_f32_16x16x32_bf16(ka1, qf1, sacc[T], 0, 0, 0);
        }

        // softmax: lane holds 20 t-values for q-row s = s0+l16
        float sc[5][4];
        float m = -1e30f;
#pragma unroll
        for (int T = 0; T < 5; ++T)
#pragma unroll
            for (int r = 0; r < 4; ++r) {
                sc[T][r] = sacc[T][r];
                m = fmaxf(m, sc[T][r]);
            }
        m = fmaxf(m, __shfl_xor(m, 16));
        m = fmaxf(m, __shfl_xor(m, 32));
        float den = 0.f;
#pragma unroll
        for (int T = 0; T < 5; ++T)
#pragma unroll
            for (int r = 0; r < 4; ++r) {
                float p = __expf(sc[T][r] - m);
                if (T == 4 && r > 0) p = (quad == 3) ? 0.f : p;  // t>=77 mask
                sc[T][r] = p;
                den += p;
            }
        den += __shfl_xor(den, 16);
        den += __shfl_xor(den, 32);
        float rden = 1.f / den;

        // write normalized P as bf16 hi+lo into per-wave swizzled LDS
#pragma unroll
        for (int T = 0; T < 5; ++T) {
#pragma unroll
            for (int r0 = 0; r0 < 4; r0 += 2) {
                float p0 = sc[T][r0] * rden, p1 = sc[T][r0 + 1] * rden;
                uint16_t h0 = f2bf(p0), h1 = f2bf(p1);
                float l0f = p0 - bf2f(h0), l1f = p1 - bf2f(h1);
                uint16_t lo0 = f2bf(l0f), lo1 = f2bf(l1f);
                int t0 = T * 16 + quad * 4 + r0;
                int byte = (t0 * 2) ^ ((l16 & 7) << 4);
                *(uint32_t*)((char*)&PhW[l16 * 128] + byte) =
                    (uint32_t)h0 | ((uint32_t)h1 << 16);
                *(uint32_t*)((char*)&PlW[l16 * 128] + byte) =
                    (uint32_t)lo0 | ((uint32_t)lo1 << 16);
            }
        }
        // same-wave LDS write->read: in-order LDS pipe + drain
        asm volatile("s_waitcnt lgkmcnt(0)" ::: "memory");

        // PV: out[s][d] = P[s][t] * V[t][d], k-dim t = 96 (3 chunks)
        short8 pa_h[3], pa_l[3];
        {
            const char* prow_h = (const char*)&PhW[l16 * 128];
            const char* prow_l = (const char*)&PlW[l16 * 128];
            int swz = (l16 & 7) << 4;
#pragma unroll
            for (int c = 0; c < 3; ++c) {
                pa_h[c] = *(const short8*)(prow_h + ((c * 64 + quad * 16) ^ swz));
                pa_l[c] = *(const short8*)(prow_l + ((c * 64 + quad * 16) ^ swz));
            }
        }
        floatx4 oacc[4];
#pragma unroll
        for (int dt = 0; dt < 4; ++dt) {
            floatx4 z = {0.f, 0.f, 0.f, 0.f};
            oacc[dt] = z;
        }
#pragma unroll
        for (int dt = 0; dt < 4; ++dt) {
            int drow = dt * 16 + l16;
            const char* vrow = (const char*)&VT[drow * 128];
            int swz = (drow & 7) << 4;
#pragma unroll
            for (int c = 0; c < 3; ++c) {
                short8 vf = *(const short8*)(vrow + ((c * 64 + quad * 16) ^ swz));
                oacc[dt] = __builtin_amdgcn_mfma_f32_16x16x32_bf16(pa_h[c], vf, oacc[dt], 0, 0, 0);
                oacc[dt] = __builtin_amdgcn_mfma_f32_16x16x32_bf16(pa_l[c], vf, oacc[dt], 0, 0, 0);
            }
        }

        // store out in place over q rows: row = s0 + quad*4 + r, col = dt*16+l16
#pragma unroll
        for (int r = 0; r < 4; ++r) {
            int s = s0 + quad * 4 + r;
            uint16_t* orow = qbuf + ((size_t)(b * 4096 + s)) * 1280 + h * 64;
#pragma unroll
            for (int dt = 0; dt < 4; ++dt) orow[dt * 16 + l16] = f2bf(oacc[dt][r]);
        }
    }
}

// ---------------------------------------------------------------------------
extern "C" void kernel_launch(void* const* d_in, const int* in_sizes, int n_in,
                              void* d_out, int out_size, void* d_ws, size_t ws_size,
                              hipStream_t stream) {
    (void)in_sizes; (void)n_in; (void)out_size; (void)ws_size;

    // workspace layout (256B-aligned)
    char* ws = (char*)d_ws;
    int* flag      = (int*)(ws + 0);
    float* AcQ     = (float*)(ws + 409856);
    float* AcK     = (float*)(ws + 819456);
    float* AcV     = (float*)(ws + 966912);
    float* AcO     = (float*)(ws + 1114368);
    float* BcQ     = (float*)(ws + 1523968);
    float* BcK     = (float*)(ws + 1605888);
    float* BcV     = (float*)(ws + 1655040);
    float* BcO     = (float*)(ws + 1704192);
    uint16_t* WqT  = (uint16_t*)(ws + 1786112);   // [1280][1280]
    uint16_t* WkT  = (uint16_t*)(ws + 5062912);   // [1280][768], contiguous with
    uint16_t* WvT  = (uint16_t*)(ws + 7028992);   //   WvT -> acts as [2560][768]
    uint16_t* WoT  = (uint16_t*)(ws + 8995072);   // [1280][1280]
    uint16_t* kvb  = (uint16_t*)(ws + 12271872);  // [616][2560] (K|V fused)
    uint16_t* qb   = (uint16_t*)(ws + 15425792);  // [32768][1280]

    // bf16 scratch for f32 inputs lives in d_out (f32-out case: 168 MB >> 85 MB
    // needed; consumed by Q/KV projections BEFORE the O-proj writes d_out).
    uint16_t* hs16  = (uint16_t*)d_out;                       // [32768][1280] bf16
    uint16_t* enc16 = (uint16_t*)((char*)d_out + 83886080);   // [616][768] bf16

    detect_dtype<<<1, 64, 0, stream>>>((const uint16_t*)d_in[0], flag);

    // Pre-convert f32 inputs to bf16 (no-op when flag==1)
    cvt_to_bf16<<<2048, 256, 0, stream>>>((const float*)d_in[0], hs16,
                                          (long)32768 * 1280, flag);
    cvt_to_bf16<<<256, 256, 0, stream>>>((const float*)d_in[1], enc16,
                                         (long)616 * 768, flag);

    // Cayley (Newton-Schulz): all 8 matrices, both dtypes, ONE launch.
    CayleyJobs cj;
    cj.W[0] = d_in[2]; cj.out[0] = AcQ;
    cj.W[1] = d_in[3]; cj.out[1] = BcQ;
    cj.W[2] = d_in[4]; cj.out[2] = AcK;
    cj.W[3] = d_in[5]; cj.out[3] = BcK;
    cj.W[4] = d_in[6]; cj.out[4] = AcV;
    cj.W[5] = d_in[7]; cj.out[5] = BcV;
    cj.W[6] = d_in[8]; cj.out[6] = AcO;
    cj.W[7] = d_in[9]; cj.out[7] = BcO;
    cayley_all<<<320, 256, 0, stream>>>(cj, flag);

    // Fold Monarch + W^T + scale -> WeffT (bf16), ONE launch for all four.
    // Q gets an extra 0.125 = dh^-0.5 (exact pow2) so attention needs no scale.
    WeffJobs wj;
    wj.W[0] = d_in[10]; wj.Ac[0] = AcQ; wj.Bc[0] = BcQ; wj.scale[0] = d_in[15];
    wj.dst[0] = WqT; wj.bdim[0] = 80; wj.Din[0] = 1280; wj.esc[0] = 0.125f;
    wj.W[1] = d_in[11]; wj.Ac[1] = AcK; wj.Bc[1] = BcK; wj.scale[1] = d_in[16];
    wj.dst[1] = WkT; wj.bdim[1] = 48; wj.Din[1] = 768; wj.esc[1] = 1.0f;
    wj.W[2] = d_in[12]; wj.Ac[2] = AcV; wj.Bc[2] = BcV; wj.scale[2] = d_in[17];
    wj.dst[2] = WvT; wj.bdim[2] = 48; wj.Din[2] = 768; wj.esc[2] = 1.0f;
    wj.W[3] = d_in[13]; wj.Ac[3] = AcO; wj.Bc[3] = BcO; wj.scale[3] = d_in[18];
    wj.dst[3] = WoT; wj.bdim[3] = 80; wj.Din[3] = 1280; wj.esc[3] = 1.0f;
    build_weff_all<<<dim3(1280, 4), 256, 0, stream>>>(wj, flag);

    // Projections (A always bf16: input-or-scratch; C bf16 internal)
    gemm_bt<<<dim3(5, 128), 512, 0, stream>>>(d_in[0], hs16, WqT, qb, nullptr,
                                              32768, 1280, 1280, flag, 0, 0);
    // K and V in ONE GEMM: B = [WkT;WvT] (contiguous), C = kvb [616][2560]
    gemm_bt<<<dim3(10, 3), 512, 0, stream>>>(d_in[1], enc16, WkT, kvb, nullptr,
                                             616, 2560, 768, flag, 0, 0);

    // Attention (in-place on qb, always bf16), MFMA path
    attn_mfma<<<dim3(16, 20, 8), 256, 0, stream>>>(kvb, qb);

    // Output projection + bias -> d_out; A = qb (bf16), out dtype follows flag
    gemm_bt<<<dim3(5, 128), 512, 0, stream>>>(qb, nullptr, WoT, d_out, d_in[14],
                                              32768, 1280, 1280, flag, 1, 1);
}